// Round 15
// baseline (3612.881 us; speedup 1.0000x reference)
//
#include <hip/hip_runtime.h>
#include <hip/hip_bf16.h>
#include <cstdint>

#define N_TOK 16384
#define DMODEL 2048
#define FFH    3072
#define NGU    (2 * FFH)   // 6144 interleaved gate/up rows
#define NEXP   8
#define ATOT   32768       // N_TOK * TOP_K

typedef __bf16 bf16;
typedef __attribute__((ext_vector_type(8))) __bf16 bf16x8;
typedef __attribute__((ext_vector_type(4))) __bf16 bf16x4;
typedef __attribute__((ext_vector_type(4))) float  f32x4;

__device__ __forceinline__ void gl_lds16(const bf16* g, void* l) {
  __builtin_amdgcn_global_load_lds(
      (const __attribute__((address_space(1))) void*)g,
      (__attribute__((address_space(3))) void*)l, 16, 0, 0);
}

// ---------------- fp32 -> bf16 conversion (down_w) ----------------
__global__ void cvt_f32_bf16(const float* __restrict__ src, bf16* __restrict__ dst, long n4) {
  long i = (long)blockIdx.x * blockDim.x + threadIdx.x;
  if (i >= n4) return;
  const float4 v = ((const float4*)src)[i];
  bf16x4 o;
  o.x = (bf16)v.x; o.y = (bf16)v.y; o.z = (bf16)v.z; o.w = (bf16)v.w;
  ((bf16x4*)dst)[i] = o;
}

// ---------------- gate/up -> interleaved bf16 buffer ----------------
__global__ void cvt_guw(const float* __restrict__ gw, const float* __restrict__ uw,
                        bf16* __restrict__ guw) {
  const long i = (long)blockIdx.x * 256 + threadIdx.x;
  const int c8 = (int)(i & 255);
  const long rg = i >> 8;
  const int e = (int)(rg / NGU);
  const int ri = (int)(rg - (long)e * NGU);
  const int hb = ri >> 6, sub = ri & 63;
  const float* src = (sub < 32 ? gw : uw) + ((size_t)e * FFH + hb * 32 + (sub & 31)) * DMODEL + c8 * 8;
  const float4 v0 = ((const float4*)src)[0];
  const float4 v1 = ((const float4*)src)[1];
  bf16x8 o;
  o[0] = (bf16)v0.x; o[1] = (bf16)v0.y; o[2] = (bf16)v0.z; o[3] = (bf16)v0.w;
  o[4] = (bf16)v1.x; o[5] = (bf16)v1.y; o[6] = (bf16)v1.z; o[7] = (bf16)v1.w;
  *(bf16x8*)(guw + rg * DMODEL + c8 * 8) = o;
}

// ------- router fused with x->bf16 conversion -------
__global__ void router_k(const float* __restrict__ x, const float* __restrict__ rw,
                         bf16* __restrict__ xb,
                         int* __restrict__ tk_e, float* __restrict__ tk_w,
                         int* __restrict__ cnt) {
  const int wv = threadIdx.x >> 6, lane = threadIdx.x & 63;
  const int t = blockIdx.x * 4 + wv;
  const float4* xr = (const float4*)(x + (size_t)t * DMODEL);
  bf16x4* xbr = (bf16x4*)(xb + (size_t)t * DMODEL);
  float acc[NEXP];
#pragma unroll
  for (int e = 0; e < NEXP; ++e) acc[e] = 0.f;
#pragma unroll
  for (int it = 0; it < DMODEL / 4 / 64; ++it) {
    const int idx = lane + it * 64;
    const float4 v = xr[idx];
    bf16x4 o;
    o.x = (bf16)v.x; o.y = (bf16)v.y; o.z = (bf16)v.z; o.w = (bf16)v.w;
    xbr[idx] = o;
#pragma unroll
    for (int e = 0; e < NEXP; ++e) {
      const float4 w = ((const float4*)(rw + e * DMODEL))[idx];
      acc[e] = fmaf(v.x, w.x, fmaf(v.y, w.y, fmaf(v.z, w.z, fmaf(v.w, w.w, acc[e]))));
    }
  }
#pragma unroll
  for (int e = 0; e < NEXP; ++e) {
#pragma unroll
    for (int o = 32; o; o >>= 1) acc[e] += __shfl_xor(acc[e], o, 64);
  }
  if (lane == 0) {
    int e0 = 0; float v0 = acc[0];
#pragma unroll
    for (int e = 1; e < NEXP; ++e) if (acc[e] > v0) { v0 = acc[e]; e0 = e; }
    int e1 = -1; float v1 = -1e30f;
#pragma unroll
    for (int e = 0; e < NEXP; ++e) if (e != e0 && acc[e] > v1) { v1 = acc[e]; e1 = e; }
    const float w0 = 1.f / (1.f + __expf(v1 - v0));
    tk_e[t * 2] = e0; tk_e[t * 2 + 1] = e1;
    tk_w[t * 2] = w0; tk_w[t * 2 + 1] = 1.f - w0;
    atomicAdd(&cnt[e0], 1); atomicAdd(&cnt[e1], 1);
  }
}

__global__ void offs_k(const int* __restrict__ cnt, int* __restrict__ offs) {
  if (threadIdx.x == 0) {
    int o = 0;
    for (int e = 0; e < NEXP; ++e) { offs[e] = o; o += cnt[e]; }
  }
}

__global__ void scatter_k(const int* __restrict__ tk_e, const float* __restrict__ tk_w,
                          const int* __restrict__ offs, int* __restrict__ cnt2,
                          int* __restrict__ tok_list, float* __restrict__ w_list,
                          int* __restrict__ aidx) {
  const int t = blockIdx.x * 256 + threadIdx.x;
  if (t >= N_TOK) return;
#pragma unroll
  for (int k = 0; k < 2; ++k) {
    const int e = tk_e[t * 2 + k];
    const int p = atomicAdd(&cnt2[e], 1);
    const int a = offs[e] + p;
    tok_list[a] = t;
    w_list[a] = tk_w[t * 2 + k];
    aidx[t * 2 + k] = a;
  }
}

// ---- GEMM1 (R15 experiment): 256x256x32, 256 thr, 4 waves of 128x128 ----
// DS-traffic cut: per wave 16 KB LDS reads per 64 MFMA (0.25 KB/MFMA vs 0.375
// in the 8-wave champion). 1 wave/SIMD; acc 256 f32 + operands ~350 regs < 512
// at __launch_bounds__(256,1) (no spill; R11's spill was a 4-wave/SIMD clamp).
// Same 3-buffer/1-barrier invariants; 8 stage loads/thread/tile -> vmcnt(8).
// LDS swizzle (conflicts=0 proven): chunk ^= (row>>1)&3 both sides; stage call q
// covers rows q*64+sr, and (q*64+sr)>>1 & 3 == (sr>>1)&3 so swz8 is q-invariant.
__global__ __launch_bounds__(256, 1) void gemm_gu(
    const bf16* __restrict__ A, const bf16* __restrict__ B,
    bf16* __restrict__ hbuf, const int* __restrict__ tok_list,
    const int* __restrict__ cnt, const int* __restrict__ offs) {
  constexpr int NT = DMODEL / 32;
  const int e = blockIdx.z;
  const int cn = cnt[e];
  const int mbase = blockIdx.y * 256;
  if (mbase >= cn) return;
  const int offE = offs[e];
  const int nbase = blockIdx.x * 256;

  __shared__ char lds[98304];
  char* const ldsA = lds;
  char* const ldsB = lds + 49152;

  const int tid = threadIdx.x;
  const int wv = tid >> 6, lane = tid & 63;
  const int wr = wv >> 1, wc = wv & 1;

  const int sr = tid >> 2;                              // 0..63
  const int swz8 = ((tid & 3) ^ ((tid >> 3) & 3)) * 8;  // chunk ^ (row>>1)&3
  const bf16* pA[4]; const bf16* pB[4];
#pragma unroll
  for (int q = 0; q < 4; ++q) {
    const int tq = tok_list[offE + min(mbase + q * 64 + sr, cn - 1)];
    pA[q] = A + (size_t)tq * DMODEL + swz8;
    pB[q] = B + ((size_t)e * NGU + nbase + q * 64 + sr) * DMODEL + swz8;
  }

  const int stageDst = tid * 16;                        // + q*4096 + buf*16384
  const int rswz = ((lane >> 4) ^ ((lane >> 1) & 3)) * 16;
  const int arow = (wr * 128 + (lane & 15)) * 64 + rswz;   // + mi*1024, mi<8
  const int brow = (wc * 128 + (lane & 15)) * 64 + rswz;   // + nf*1024, nf<8

  const f32x4 zero = {0.f, 0.f, 0.f, 0.f};
  f32x4 acc[8][8];
#pragma unroll
  for (int i = 0; i < 8; ++i)
#pragma unroll
    for (int j = 0; j < 8; ++j) acc[i][j] = zero;

  auto stage = [&](int buf, int qh, int kt) {  // qh 0-3: A quarters; 4-7: B quarters
    const int k8 = kt * 32;
    if (qh < 4) gl_lds16(pA[qh] + k8, ldsA + buf * 16384 + qh * 4096 + stageDst);
    else        gl_lds16(pB[qh - 4] + k8, ldsB + buf * 16384 + (qh - 4) * 4096 + stageDst);
  };

#pragma unroll
  for (int qh = 0; qh < 8; ++qh) stage(0, qh, 0);
#pragma unroll
  for (int qh = 0; qh < 8; ++qh) stage(1, qh, 1);
  asm volatile("s_waitcnt vmcnt(8)" ::: "memory");
  __builtin_amdgcn_s_barrier();
  asm volatile("" ::: "memory");

  int cb = 0;
  for (int kt = 0; kt < NT; ++kt) {
    const int sb = (cb + 2 >= 3) ? cb - 1 : cb + 2;
    const char* cA = ldsA + cb * 16384;
    const char* cB = ldsB + cb * 16384;

    bf16x8 a[8], b[8];
#pragma unroll
    for (int i = 0; i < 8; ++i) {
      a[i] = *(const bf16x8*)(cA + i * 1024 + arow);
      b[i] = *(const bf16x8*)(cB + i * 1024 + brow);
    }

    if (kt + 2 < NT) {
      stage(sb, 0, kt + 2); stage(sb, 1, kt + 2);
      stage(sb, 2, kt + 2); stage(sb, 3, kt + 2);
    }

    __builtin_amdgcn_s_setprio(1);
#pragma unroll
    for (int nf = 0; nf < 4; ++nf)
#pragma unroll
      for (int mi = 0; mi < 8; ++mi)
        acc[mi][nf] = __builtin_amdgcn_mfma_f32_16x16x32_bf16(a[mi], b[nf], acc[mi][nf], 0, 0, 0);
    __builtin_amdgcn_s_setprio(0);

    if (kt + 2 < NT) {
      stage(sb, 4, kt + 2); stage(sb, 5, kt + 2);
      stage(sb, 6, kt + 2); stage(sb, 7, kt + 2);
    }

    __builtin_amdgcn_s_setprio(1);
#pragma unroll
    for (int nf = 4; nf < 8; ++nf)
#pragma unroll
      for (int mi = 0; mi < 8; ++mi)
        acc[mi][nf] = __builtin_amdgcn_mfma_f32_16x16x32_bf16(a[mi], b[nf], acc[mi][nf], 0, 0, 0);
    __builtin_amdgcn_s_setprio(0);

    if (kt + 2 < NT) { asm volatile("s_waitcnt vmcnt(8)" ::: "memory"); }
    else             { asm volatile("s_waitcnt vmcnt(0)" ::: "memory"); }
    asm volatile("" ::: "memory");
    __builtin_amdgcn_s_barrier();
    asm volatile("" ::: "memory");

    cb = (cb + 1 == 3) ? 0 : cb + 1;
  }

  // epilogue: wave 128-col stripe = two 64-blocks of [32 gate | 32 up]
  const int col = lane & 15;
  const int rb = mbase + wr * 128 + (lane >> 4) * 4;
#pragma unroll
  for (int mi = 0; mi < 8; ++mi)
#pragma unroll
    for (int j = 0; j < 4; ++j) {
      const int row = rb + mi * 16 + j;
      if (row < cn) {
        bf16* hrow = hbuf + (size_t)(offE + row) * FFH;
#pragma unroll
        for (int b2 = 0; b2 < 2; ++b2) {
          const int hb32 = ((nbase + wc * 128 + b2 * 64) >> 6) * 32;
#pragma unroll
          for (int k = 0; k < 2; ++k) {
            const float g = acc[mi][b2 * 4 + k][j], u = acc[mi][b2 * 4 + 2 + k][j];
            hrow[hb32 + col + k * 16] = (bf16)(g / (1.f + __expf(-g)) * u);
          }
        }
      }
    }
}

// GEMM2: 256x256x32 champion (unchanged). A = hbuf rows, B = dwb, epi -> ybuf bf16 = w*y
__global__ __launch_bounds__(512, 2) void gemm_dn(
    const bf16* __restrict__ A, const bf16* __restrict__ B,
    bf16* __restrict__ ybuf, const float* __restrict__ w_list,
    const int* __restrict__ cnt, const int* __restrict__ offs) {
  constexpr int NT = FFH / 32;
  const int e = blockIdx.z;
  const int cn = cnt[e];
  const int mbase = blockIdx.y * 256;
  if (mbase >= cn) return;
  const int offE = offs[e];
  const int nbase = blockIdx.x * 256;

  __shared__ char lds[98304];
  char* const ldsA = lds;
  char* const ldsB = lds + 49152;

  const int tid = threadIdx.x;
  const int wv = tid >> 6, lane = tid & 63;
  const int wr = wv >> 2, wc = wv & 3;

  const int sr = tid >> 2;
  const int swz8 = ((tid & 3) ^ ((tid >> 3) & 3)) * 8;
  const int a0 = offE + min(mbase + sr, cn - 1);
  const int a1 = offE + min(mbase + 128 + sr, cn - 1);
  const bf16* pA[2] = { A + (size_t)a0 * FFH + swz8, A + (size_t)a1 * FFH + swz8 };
  const bf16* pB[2] = { B + ((size_t)e * DMODEL + nbase + sr) * FFH + swz8,
                        B + ((size_t)e * DMODEL + nbase + 128 + sr) * FFH + swz8 };

  const int stageDst = wv * 1024;
  const int rswz = ((lane >> 4) ^ ((lane >> 1) & 3)) * 16;
  const int arow = (wr * 128 + (lane & 15)) * 64 + rswz;
  const int brow = (wc * 64 + (lane & 15)) * 64 + rswz;

  const f32x4 zero = {0.f, 0.f, 0.f, 0.f};
  f32x4 acc[8][4];
#pragma unroll
  for (int i = 0; i < 8; ++i)
#pragma unroll
    for (int j = 0; j < 4; ++j) acc[i][j] = zero;

  auto stage_half = [&](int buf, int qh, int kt) {
    const int k8 = kt * 32;
    if (qh < 2) gl_lds16(pA[qh] + k8, ldsA + buf * 16384 + qh * 8192 + stageDst);
    else        gl_lds16(pB[qh - 2] + k8, ldsB + buf * 16384 + (qh - 2) * 8192 + stageDst);
  };

#pragma unroll
  for (int qh = 0; qh < 4; ++qh) stage_half(0, qh, 0);
#pragma unroll
  for (int qh = 0; qh < 4; ++qh) stage_half(1, qh, 1);
  asm volatile("s_waitcnt vmcnt(4)" ::: "memory");
  __builtin_amdgcn_s_barrier();
  asm volatile("" ::: "memory");

  int cb = 0;
  for (int kt = 0; kt < NT; ++kt) {
    const int sb = (cb + 2 >= 3) ? cb - 1 : cb + 2;
    const char* cA = ldsA + cb * 16384;
    const char* cB = ldsB + cb * 16384;

    bf16x8 a[8], b[4];
#pragma unroll
    for (int i = 0; i < 4; ++i) {
      a[i] = *(const bf16x8*)(cA + i * 1024 + arow);
      b[i] = *(const bf16x8*)(cB + i * 1024 + brow);
    }
#pragma unroll
    for (int i = 4; i < 8; ++i) a[i] = *(const bf16x8*)(cA + i * 1024 + arow);

    if (kt + 2 < NT) { stage_half(sb, 0, kt + 2); stage_half(sb, 1, kt + 2); }

    __builtin_amdgcn_s_setprio(1);
#pragma unroll
    for (int nf = 0; nf < 4; ++nf)
#pragma unroll
      for (int mi = 0; mi < 4; ++mi)
        acc[mi][nf] = __builtin_amdgcn_mfma_f32_16x16x32_bf16(a[mi], b[nf], acc[mi][nf], 0, 0, 0);
    __builtin_amdgcn_s_setprio(0);

    if (kt + 2 < NT) { stage_half(sb, 2, kt + 2); stage_half(sb, 3, kt + 2); }

    __builtin_amdgcn_s_setprio(1);
#pragma unroll
    for (int nf = 0; nf < 4; ++nf)
#pragma unroll
      for (int mi = 4; mi < 8; ++mi)
        acc[mi][nf] = __builtin_amdgcn_mfma_f32_16x16x32_bf16(a[mi], b[nf], acc[mi][nf], 0, 0, 0);
    __builtin_amdgcn_s_setprio(0);

    if (kt + 2 < NT) { asm volatile("s_waitcnt vmcnt(4)" ::: "memory"); }
    else             { asm volatile("s_waitcnt vmcnt(0)" ::: "memory"); }
    asm volatile("" ::: "memory");
    __builtin_amdgcn_s_barrier();
    asm volatile("" ::: "memory");

    cb = (cb + 1 == 3) ? 0 : cb + 1;
  }

  const int col = lane & 15;
  const int rb = mbase + wr * 128 + (lane >> 4) * 4;
#pragma unroll
  for (int mi = 0; mi < 8; ++mi)
#pragma unroll
    for (int j = 0; j < 4; ++j) {
      const int row = rb + mi * 16 + j;
      if (row < cn) {
        const float wg = w_list[offE + row];
        bf16* yr = ybuf + (size_t)(offE + row) * DMODEL + nbase + wc * 64 + col;
#pragma unroll
        for (int nf = 0; nf < 4; ++nf) yr[nf * 16] = (bf16)(wg * acc[mi][nf][j]);
      }
    }
}

// ---------------- final combine: out[t] = y[a0] + y[a1] (w pre-applied) ----------------
__global__ void combine_k(const bf16* __restrict__ ybuf, const int* __restrict__ aidx,
                          float* __restrict__ out) {
  const int i = blockIdx.x * 256 + threadIdx.x;   // N_TOK*256 threads, 8 elems each
  const int t = i >> 8, c = i & 255;
  const int a0 = aidx[t * 2], a1 = aidx[t * 2 + 1];
  const bf16x8 v0 = ((const bf16x8*)(ybuf + (size_t)a0 * DMODEL))[c];
  const bf16x8 v1 = ((const bf16x8*)(ybuf + (size_t)a1 * DMODEL))[c];
  float4 o0, o1;
  o0.x = (float)v0[0] + (float)v1[0];
  o0.y = (float)v0[1] + (float)v1[1];
  o0.z = (float)v0[2] + (float)v1[2];
  o0.w = (float)v0[3] + (float)v1[3];
  o1.x = (float)v0[4] + (float)v1[4];
  o1.y = (float)v0[5] + (float)v1[5];
  o1.z = (float)v0[6] + (float)v1[6];
  o1.w = (float)v0[7] + (float)v1[7];
  float4* op = (float4*)(out + (size_t)t * DMODEL + c * 8);
  op[0] = o0; op[1] = o1;
}

extern "C" void kernel_launch(void* const* d_in, const int* in_sizes, int n_in,
                              void* d_out, int out_size, void* d_ws, size_t ws_size,
                              hipStream_t stream) {
  const float* x  = (const float*)d_in[0];
  const float* rw = (const float*)d_in[1];
  const float* gw = (const float*)d_in[2];
  const float* uw = (const float*)d_in[3];
  const float* dw = (const float*)d_in[4];
  float* out = (float*)d_out;

  char* ws = (char*)d_ws;
  size_t o = 0;
  auto alloc = [&](size_t bytes) {
    void* p = ws + o;
    o = (o + bytes + 255) & ~(size_t)255;
    return p;
  };

  const size_t guw_bytes  = (size_t)NEXP * NGU * DMODEL * 2;          // 201.3 MB
  const size_t ybuf_bytes = (size_t)(ATOT + 256) * DMODEL * 2;        // 135 MB
  bf16*  xb       = (bf16*)alloc((size_t)N_TOK * DMODEL * 2);         // 67 MB
  void*  uni      = alloc(guw_bytes > ybuf_bytes ? guw_bytes : ybuf_bytes);
  bf16*  guw      = (bf16*)uni;     // live: cvt..gemm1
  bf16*  ybuf     = (bf16*)uni;     // live: gemm2..combine
  bf16*  dwb      = (bf16*)alloc((size_t)NEXP * DMODEL * FFH * 2);    // 100.7 MB
  bf16*  hbuf     = (bf16*)alloc((size_t)(ATOT + 256) * FFH * 2);     // 202.9 MB
  int*   tok_list = (int*)alloc((ATOT + 256) * 4);
  float* w_list   = (float*)alloc((ATOT + 256) * 4);
  int*   tk_e     = (int*)alloc((size_t)N_TOK * 2 * 4);
  float* tk_w     = (float*)alloc((size_t)N_TOK * 2 * 4);
  int*   aidx     = (int*)alloc((size_t)N_TOK * 2 * 4);
  int*   cnt      = (int*)alloc(64);
  int*   offs     = (int*)alloc(64);
  int*   cnt2     = (int*)alloc(64);

  hipMemsetAsync(cnt, 0, 64, stream);
  hipMemsetAsync(cnt2, 0, 64, stream);

  // routing (+ fused x->bf16)
  router_k<<<N_TOK / 4, 256, 0, stream>>>(x, rw, xb, tk_e, tk_w, cnt);
  offs_k<<<1, 64, 0, stream>>>(cnt, offs);
  scatter_k<<<N_TOK / 256, 256, 0, stream>>>(tk_e, tk_w, offs, cnt2, tok_list, w_list, aidx);

  // weight conversions (bf16 pays off: GEMMs re-read B panels many times)
  cvt_guw<<<(unsigned)((long)NEXP * NGU * DMODEL / 8 / 256), 256, 0, stream>>>(gw, uw, guw);
  {
    long n4 = (long)NEXP * DMODEL * FFH / 4;
    cvt_f32_bf16<<<(unsigned)(n4 / 256), 256, 0, stream>>>(dw, dwb, n4);
  }

  // expert GEMMs (m-grid covers worst case cn=16384 -> 64 tiles of 256; empty exit)
  gemm_gu<<<dim3(NGU / 256, 64, NEXP), 256, 0, stream>>>(
      xb, guw, hbuf, tok_list, cnt, offs);
  gemm_dn<<<dim3(DMODEL / 256, 64, NEXP), 512, 0, stream>>>(
      hbuf, dwb, ybuf, w_list, cnt, offs);

  // combine (fully overwrites d_out every call)
  combine_k<<<N_TOK, 256, 0, stream>>>(ybuf, aidx, out);
}

// Round 16
// 1927.802 us; speedup vs baseline: 1.8741x; 1.8741x over previous
//
#include <hip/hip_runtime.h>
#include <hip/hip_bf16.h>
#include <cstdint>

#define N_TOK 16384
#define DMODEL 2048
#define FFH    3072
#define NGU    (2 * FFH)   // 6144 interleaved gate/up rows
#define NEXP   8
#define ATOT   32768       // N_TOK * TOP_K

typedef __bf16 bf16;
typedef __attribute__((ext_vector_type(8))) __bf16 bf16x8;
typedef __attribute__((ext_vector_type(4))) __bf16 bf16x4;
typedef __attribute__((ext_vector_type(4))) float  f32x4;

__device__ __forceinline__ void gl_lds16(const bf16* g, void* l) {
  __builtin_amdgcn_global_load_lds(
      (const __attribute__((address_space(1))) void*)g,
      (__attribute__((address_space(3))) void*)l, 16, 0, 0);
}

// ---------------- fp32 -> bf16 conversion (down_w) ----------------
__global__ void cvt_f32_bf16(const float* __restrict__ src, bf16* __restrict__ dst, long n4) {
  long i = (long)blockIdx.x * blockDim.x + threadIdx.x;
  if (i >= n4) return;
  const float4 v = ((const float4*)src)[i];
  bf16x4 o;
  o.x = (bf16)v.x; o.y = (bf16)v.y; o.z = (bf16)v.z; o.w = (bf16)v.w;
  ((bf16x4*)dst)[i] = o;
}

// ---------------- gate/up -> interleaved bf16 buffer ----------------
__global__ void cvt_guw(const float* __restrict__ gw, const float* __restrict__ uw,
                        bf16* __restrict__ guw) {
  const long i = (long)blockIdx.x * 256 + threadIdx.x;
  const int c8 = (int)(i & 255);
  const long rg = i >> 8;
  const int e = (int)(rg / NGU);
  const int ri = (int)(rg - (long)e * NGU);
  const int hb = ri >> 6, sub = ri & 63;
  const float* src = (sub < 32 ? gw : uw) + ((size_t)e * FFH + hb * 32 + (sub & 31)) * DMODEL + c8 * 8;
  const float4 v0 = ((const float4*)src)[0];
  const float4 v1 = ((const float4*)src)[1];
  bf16x8 o;
  o[0] = (bf16)v0.x; o[1] = (bf16)v0.y; o[2] = (bf16)v0.z; o[3] = (bf16)v0.w;
  o[4] = (bf16)v1.x; o[5] = (bf16)v1.y; o[6] = (bf16)v1.z; o[7] = (bf16)v1.w;
  *(bf16x8*)(guw + rg * DMODEL + c8 * 8) = o;
}

// ------- router fused with x->bf16 conversion -------
__global__ void router_k(const float* __restrict__ x, const float* __restrict__ rw,
                         bf16* __restrict__ xb,
                         int* __restrict__ tk_e, float* __restrict__ tk_w,
                         int* __restrict__ cnt) {
  const int wv = threadIdx.x >> 6, lane = threadIdx.x & 63;
  const int t = blockIdx.x * 4 + wv;
  const float4* xr = (const float4*)(x + (size_t)t * DMODEL);
  bf16x4* xbr = (bf16x4*)(xb + (size_t)t * DMODEL);
  float acc[NEXP];
#pragma unroll
  for (int e = 0; e < NEXP; ++e) acc[e] = 0.f;
#pragma unroll
  for (int it = 0; it < DMODEL / 4 / 64; ++it) {
    const int idx = lane + it * 64;
    const float4 v = xr[idx];
    bf16x4 o;
    o.x = (bf16)v.x; o.y = (bf16)v.y; o.z = (bf16)v.z; o.w = (bf16)v.w;
    xbr[idx] = o;
#pragma unroll
    for (int e = 0; e < NEXP; ++e) {
      const float4 w = ((const float4*)(rw + e * DMODEL))[idx];
      acc[e] = fmaf(v.x, w.x, fmaf(v.y, w.y, fmaf(v.z, w.z, fmaf(v.w, w.w, acc[e]))));
    }
  }
#pragma unroll
  for (int e = 0; e < NEXP; ++e) {
#pragma unroll
    for (int o = 32; o; o >>= 1) acc[e] += __shfl_xor(acc[e], o, 64);
  }
  if (lane == 0) {
    int e0 = 0; float v0 = acc[0];
#pragma unroll
    for (int e = 1; e < NEXP; ++e) if (acc[e] > v0) { v0 = acc[e]; e0 = e; }
    int e1 = -1; float v1 = -1e30f;
#pragma unroll
    for (int e = 0; e < NEXP; ++e) if (e != e0 && acc[e] > v1) { v1 = acc[e]; e1 = e; }
    const float w0 = 1.f / (1.f + __expf(v1 - v0));
    tk_e[t * 2] = e0; tk_e[t * 2 + 1] = e1;
    tk_w[t * 2] = w0; tk_w[t * 2 + 1] = 1.f - w0;
    atomicAdd(&cnt[e0], 1); atomicAdd(&cnt[e1], 1);
  }
}

__global__ void offs_k(const int* __restrict__ cnt, int* __restrict__ offs) {
  if (threadIdx.x == 0) {
    int o = 0;
    for (int e = 0; e < NEXP; ++e) { offs[e] = o; o += cnt[e]; }
  }
}

__global__ void scatter_k(const int* __restrict__ tk_e, const float* __restrict__ tk_w,
                          const int* __restrict__ offs, int* __restrict__ cnt2,
                          int* __restrict__ tok_list, float* __restrict__ w_list,
                          int* __restrict__ aidx) {
  const int t = blockIdx.x * 256 + threadIdx.x;
  if (t >= N_TOK) return;
#pragma unroll
  for (int k = 0; k < 2; ++k) {
    const int e = tk_e[t * 2 + k];
    const int p = atomicAdd(&cnt2[e], 1);
    const int a = offs[e] + p;
    tok_list[a] = t;
    w_list[a] = tk_w[t * 2 + k];
    aidx[t * 2 + k] = a;
  }
}

// ---------------- 256x256x32 3-buffer MFMA GEMM core (R4/R9 champion) ----------------
// Natural block mapping (no XCD swizzle: R8 A/B showed swizzle doubles FETCH).
// Race invariants: iter t reads cb, stages sb = buffer read at t-1 (freed by the
// end-of-iter barrier); vmcnt(4) leaves only tile t+2's loads in flight -> tile
// t+1 landed; barrier publishes. LDS swizzle (conflicts=0): chunk ^= (row>>1)&3.
// Wave tile 128x64 (acc=128 f32) is the largest spill-free shape: R15 measured
// the 128x128 variant clamping at the 256-VGPR/wave HW ceiling and spilling.

// GEMM1: A = xb gathered by tok_list, B = guw (N=6144), epi silu(g)*u -> hbuf bf16
__global__ __launch_bounds__(512, 2) void gemm_gu(
    const bf16* __restrict__ A, const bf16* __restrict__ B,
    bf16* __restrict__ hbuf, const int* __restrict__ tok_list,
    const int* __restrict__ cnt, const int* __restrict__ offs) {
  constexpr int NT = DMODEL / 32;
  const int e = blockIdx.z;
  const int cn = cnt[e];
  const int mbase = blockIdx.y * 256;
  if (mbase >= cn) return;
  const int offE = offs[e];
  const int nbase = blockIdx.x * 256;

  __shared__ char lds[98304];
  char* const ldsA = lds;
  char* const ldsB = lds + 49152;

  const int tid = threadIdx.x;
  const int wv = tid >> 6, lane = tid & 63;
  const int wr = wv >> 2, wc = wv & 3;

  const int sr = tid >> 2;
  const int swz8 = ((tid & 3) ^ ((tid >> 3) & 3)) * 8;
  const int t0 = tok_list[offE + min(mbase + sr, cn - 1)];
  const int t1 = tok_list[offE + min(mbase + 128 + sr, cn - 1)];
  const bf16* pA[2] = { A + (size_t)t0 * DMODEL + swz8, A + (size_t)t1 * DMODEL + swz8 };
  const bf16* pB[2] = { B + ((size_t)e * NGU + nbase + sr) * DMODEL + swz8,
                        B + ((size_t)e * NGU + nbase + 128 + sr) * DMODEL + swz8 };

  const int stageDst = wv * 1024;
  const int rswz = ((lane >> 4) ^ ((lane >> 1) & 3)) * 16;
  const int arow = (wr * 128 + (lane & 15)) * 64 + rswz;
  const int brow = (wc * 64 + (lane & 15)) * 64 + rswz;

  const f32x4 zero = {0.f, 0.f, 0.f, 0.f};
  f32x4 acc[8][4];
#pragma unroll
  for (int i = 0; i < 8; ++i)
#pragma unroll
    for (int j = 0; j < 4; ++j) acc[i][j] = zero;

  auto stage_half = [&](int buf, int qh, int kt) {
    const int k8 = kt * 32;
    if (qh < 2) gl_lds16(pA[qh] + k8, ldsA + buf * 16384 + qh * 8192 + stageDst);
    else        gl_lds16(pB[qh - 2] + k8, ldsB + buf * 16384 + (qh - 2) * 8192 + stageDst);
  };

#pragma unroll
  for (int qh = 0; qh < 4; ++qh) stage_half(0, qh, 0);
#pragma unroll
  for (int qh = 0; qh < 4; ++qh) stage_half(1, qh, 1);
  asm volatile("s_waitcnt vmcnt(4)" ::: "memory");
  __builtin_amdgcn_s_barrier();
  asm volatile("" ::: "memory");

  int cb = 0;
  for (int kt = 0; kt < NT; ++kt) {
    const int sb = (cb + 2 >= 3) ? cb - 1 : cb + 2;
    const char* cA = ldsA + cb * 16384;
    const char* cB = ldsB + cb * 16384;

    bf16x8 a[8], b[4];
#pragma unroll
    for (int i = 0; i < 4; ++i) {
      a[i] = *(const bf16x8*)(cA + i * 1024 + arow);
      b[i] = *(const bf16x8*)(cB + i * 1024 + brow);
    }
#pragma unroll
    for (int i = 4; i < 8; ++i) a[i] = *(const bf16x8*)(cA + i * 1024 + arow);

    if (kt + 2 < NT) { stage_half(sb, 0, kt + 2); stage_half(sb, 1, kt + 2); }

    __builtin_amdgcn_s_setprio(1);
#pragma unroll
    for (int nf = 0; nf < 4; ++nf)
#pragma unroll
      for (int mi = 0; mi < 4; ++mi)
        acc[mi][nf] = __builtin_amdgcn_mfma_f32_16x16x32_bf16(a[mi], b[nf], acc[mi][nf], 0, 0, 0);
    __builtin_amdgcn_s_setprio(0);

    if (kt + 2 < NT) { stage_half(sb, 2, kt + 2); stage_half(sb, 3, kt + 2); }

    __builtin_amdgcn_s_setprio(1);
#pragma unroll
    for (int nf = 0; nf < 4; ++nf)
#pragma unroll
      for (int mi = 4; mi < 8; ++mi)
        acc[mi][nf] = __builtin_amdgcn_mfma_f32_16x16x32_bf16(a[mi], b[nf], acc[mi][nf], 0, 0, 0);
    __builtin_amdgcn_s_setprio(0);

    if (kt + 2 < NT) { asm volatile("s_waitcnt vmcnt(4)" ::: "memory"); }
    else             { asm volatile("s_waitcnt vmcnt(0)" ::: "memory"); }
    asm volatile("" ::: "memory");
    __builtin_amdgcn_s_barrier();
    asm volatile("" ::: "memory");

    cb = (cb + 1 == 3) ? 0 : cb + 1;
  }

  const int col = lane & 15;
  const int rb = mbase + wr * 128 + (lane >> 4) * 4;
  const int hb32 = ((nbase + wc * 64) >> 6) * 32;
#pragma unroll
  for (int mi = 0; mi < 8; ++mi)
#pragma unroll
    for (int j = 0; j < 4; ++j) {
      const int row = rb + mi * 16 + j;
      if (row < cn) {
        bf16* hr = hbuf + (size_t)(offE + row) * FFH + hb32 + col;
#pragma unroll
        for (int k = 0; k < 2; ++k) {
          const float g = acc[mi][k][j], u = acc[mi][k + 2][j];
          hr[k * 16] = (bf16)(g / (1.f + __expf(-g)) * u);
        }
      }
    }
}

// GEMM2: A = hbuf (assignment rows), B = dwb (N=2048), epi -> ybuf bf16 = w*y
__global__ __launch_bounds__(512, 2) void gemm_dn(
    const bf16* __restrict__ A, const bf16* __restrict__ B,
    bf16* __restrict__ ybuf, const float* __restrict__ w_list,
    const int* __restrict__ cnt, const int* __restrict__ offs) {
  constexpr int NT = FFH / 32;
  const int e = blockIdx.z;
  const int cn = cnt[e];
  const int mbase = blockIdx.y * 256;
  if (mbase >= cn) return;
  const int offE = offs[e];
  const int nbase = blockIdx.x * 256;

  __shared__ char lds[98304];
  char* const ldsA = lds;
  char* const ldsB = lds + 49152;

  const int tid = threadIdx.x;
  const int wv = tid >> 6, lane = tid & 63;
  const int wr = wv >> 2, wc = wv & 3;

  const int sr = tid >> 2;
  const int swz8 = ((tid & 3) ^ ((tid >> 3) & 3)) * 8;
  const int a0 = offE + min(mbase + sr, cn - 1);
  const int a1 = offE + min(mbase + 128 + sr, cn - 1);
  const bf16* pA[2] = { A + (size_t)a0 * FFH + swz8, A + (size_t)a1 * FFH + swz8 };
  const bf16* pB[2] = { B + ((size_t)e * DMODEL + nbase + sr) * FFH + swz8,
                        B + ((size_t)e * DMODEL + nbase + 128 + sr) * FFH + swz8 };

  const int stageDst = wv * 1024;
  const int rswz = ((lane >> 4) ^ ((lane >> 1) & 3)) * 16;
  const int arow = (wr * 128 + (lane & 15)) * 64 + rswz;
  const int brow = (wc * 64 + (lane & 15)) * 64 + rswz;

  const f32x4 zero = {0.f, 0.f, 0.f, 0.f};
  f32x4 acc[8][4];
#pragma unroll
  for (int i = 0; i < 8; ++i)
#pragma unroll
    for (int j = 0; j < 4; ++j) acc[i][j] = zero;

  auto stage_half = [&](int buf, int qh, int kt) {
    const int k8 = kt * 32;
    if (qh < 2) gl_lds16(pA[qh] + k8, ldsA + buf * 16384 + qh * 8192 + stageDst);
    else        gl_lds16(pB[qh - 2] + k8, ldsB + buf * 16384 + (qh - 2) * 8192 + stageDst);
  };

#pragma unroll
  for (int qh = 0; qh < 4; ++qh) stage_half(0, qh, 0);
#pragma unroll
  for (int qh = 0; qh < 4; ++qh) stage_half(1, qh, 1);
  asm volatile("s_waitcnt vmcnt(4)" ::: "memory");
  __builtin_amdgcn_s_barrier();
  asm volatile("" ::: "memory");

  int cb = 0;
  for (int kt = 0; kt < NT; ++kt) {
    const int sb = (cb + 2 >= 3) ? cb - 1 : cb + 2;
    const char* cA = ldsA + cb * 16384;
    const char* cB = ldsB + cb * 16384;

    bf16x8 a[8], b[4];
#pragma unroll
    for (int i = 0; i < 4; ++i) {
      a[i] = *(const bf16x8*)(cA + i * 1024 + arow);
      b[i] = *(const bf16x8*)(cB + i * 1024 + brow);
    }
#pragma unroll
    for (int i = 4; i < 8; ++i) a[i] = *(const bf16x8*)(cA + i * 1024 + arow);

    if (kt + 2 < NT) { stage_half(sb, 0, kt + 2); stage_half(sb, 1, kt + 2); }

    __builtin_amdgcn_s_setprio(1);
#pragma unroll
    for (int nf = 0; nf < 4; ++nf)
#pragma unroll
      for (int mi = 0; mi < 4; ++mi)
        acc[mi][nf] = __builtin_amdgcn_mfma_f32_16x16x32_bf16(a[mi], b[nf], acc[mi][nf], 0, 0, 0);
    __builtin_amdgcn_s_setprio(0);

    if (kt + 2 < NT) { stage_half(sb, 2, kt + 2); stage_half(sb, 3, kt + 2); }

    __builtin_amdgcn_s_setprio(1);
#pragma unroll
    for (int nf = 0; nf < 4; ++nf)
#pragma unroll
      for (int mi = 4; mi < 8; ++mi)
        acc[mi][nf] = __builtin_amdgcn_mfma_f32_16x16x32_bf16(a[mi], b[nf], acc[mi][nf], 0, 0, 0);
    __builtin_amdgcn_s_setprio(0);

    if (kt + 2 < NT) { asm volatile("s_waitcnt vmcnt(4)" ::: "memory"); }
    else             { asm volatile("s_waitcnt vmcnt(0)" ::: "memory"); }
    asm volatile("" ::: "memory");
    __builtin_amdgcn_s_barrier();
    asm volatile("" ::: "memory");

    cb = (cb + 1 == 3) ? 0 : cb + 1;
  }

  const int col = lane & 15;
  const int rb = mbase + wr * 128 + (lane >> 4) * 4;
#pragma unroll
  for (int mi = 0; mi < 8; ++mi)
#pragma unroll
    for (int j = 0; j < 4; ++j) {
      const int row = rb + mi * 16 + j;
      if (row < cn) {
        const float wg = w_list[offE + row];
        bf16* yr = ybuf + (size_t)(offE + row) * DMODEL + nbase + wc * 64 + col;
#pragma unroll
        for (int nf = 0; nf < 4; ++nf) yr[nf * 16] = (bf16)(wg * acc[mi][nf][j]);
      }
    }
}

// ---------------- final combine: out[t] = y[a0] + y[a1] (w pre-applied) ----------------
__global__ void combine_k(const bf16* __restrict__ ybuf, const int* __restrict__ aidx,
                          float* __restrict__ out) {
  const int i = blockIdx.x * 256 + threadIdx.x;   // N_TOK*256 threads, 8 elems each
  const int t = i >> 8, c = i & 255;
  const int a0 = aidx[t * 2], a1 = aidx[t * 2 + 1];
  const bf16x8 v0 = ((const bf16x8*)(ybuf + (size_t)a0 * DMODEL))[c];
  const bf16x8 v1 = ((const bf16x8*)(ybuf + (size_t)a1 * DMODEL))[c];
  float4 o0, o1;
  o0.x = (float)v0[0] + (float)v1[0];
  o0.y = (float)v0[1] + (float)v1[1];
  o0.z = (float)v0[2] + (float)v1[2];
  o0.w = (float)v0[3] + (float)v1[3];
  o1.x = (float)v0[4] + (float)v1[4];
  o1.y = (float)v0[5] + (float)v1[5];
  o1.z = (float)v0[6] + (float)v1[6];
  o1.w = (float)v0[7] + (float)v1[7];
  float4* op = (float4*)(out + (size_t)t * DMODEL + c * 8);
  op[0] = o0; op[1] = o1;
}

extern "C" void kernel_launch(void* const* d_in, const int* in_sizes, int n_in,
                              void* d_out, int out_size, void* d_ws, size_t ws_size,
                              hipStream_t stream) {
  const float* x  = (const float*)d_in[0];
  const float* rw = (const float*)d_in[1];
  const float* gw = (const float*)d_in[2];
  const float* uw = (const float*)d_in[3];
  const float* dw = (const float*)d_in[4];
  float* out = (float*)d_out;

  char* ws = (char*)d_ws;
  size_t o = 0;
  auto alloc = [&](size_t bytes) {
    void* p = ws + o;
    o = (o + bytes + 255) & ~(size_t)255;
    return p;
  };

  const size_t guw_bytes  = (size_t)NEXP * NGU * DMODEL * 2;          // 201.3 MB
  const size_t ybuf_bytes = (size_t)(ATOT + 256) * DMODEL * 2;        // 135 MB
  bf16*  xb       = (bf16*)alloc((size_t)N_TOK * DMODEL * 2);         // 67 MB
  void*  uni      = alloc(guw_bytes > ybuf_bytes ? guw_bytes : ybuf_bytes);
  bf16*  guw      = (bf16*)uni;     // live: cvt..gemm1
  bf16*  ybuf     = (bf16*)uni;     // live: gemm2..combine
  bf16*  dwb      = (bf16*)alloc((size_t)NEXP * DMODEL * FFH * 2);    // 100.7 MB
  bf16*  hbuf     = (bf16*)alloc((size_t)(ATOT + 256) * FFH * 2);     // 202.9 MB
  int*   tok_list = (int*)alloc((ATOT + 256) * 4);
  float* w_list   = (float*)alloc((ATOT + 256) * 4);
  int*   tk_e     = (int*)alloc((size_t)N_TOK * 2 * 4);
  float* tk_w     = (float*)alloc((size_t)N_TOK * 2 * 4);
  int*   aidx     = (int*)alloc((size_t)N_TOK * 2 * 4);
  int*   cnt      = (int*)alloc(64);
  int*   offs     = (int*)alloc(64);
  int*   cnt2     = (int*)alloc(64);

  hipMemsetAsync(cnt, 0, 64, stream);
  hipMemsetAsync(cnt2, 0, 64, stream);

  // routing (+ fused x->bf16)
  router_k<<<N_TOK / 4, 256, 0, stream>>>(x, rw, xb, tk_e, tk_w, cnt);
  offs_k<<<1, 64, 0, stream>>>(cnt, offs);
  scatter_k<<<N_TOK / 256, 256, 0, stream>>>(tk_e, tk_w, offs, cnt2, tok_list, w_list, aidx);

  // weight conversions (bf16 pays off: GEMMs re-read B panels many times)
  cvt_guw<<<(unsigned)((long)NEXP * NGU * DMODEL / 8 / 256), 256, 0, stream>>>(gw, uw, guw);
  {
    long n4 = (long)NEXP * DMODEL * FFH / 4;
    cvt_f32_bf16<<<(unsigned)(n4 / 256), 256, 0, stream>>>(dw, dwb, n4);
  }

  // expert GEMMs (m-grid covers worst case cn=16384 -> 64 tiles of 256; empty exit)
  gemm_gu<<<dim3(NGU / 256, 64, NEXP), 512, 0, stream>>>(
      xb, guw, hbuf, tok_list, cnt, offs);
  gemm_dn<<<dim3(DMODEL / 256, 64, NEXP), 512, 0, stream>>>(
      hbuf, dwb, ybuf, w_list, cnt, offs);

  // combine (fully overwrites d_out every call)
  combine_k<<<N_TOK, 256, 0, stream>>>(ybuf, aidx, out);
}